// Round 1
// 174.441 us; speedup vs baseline: 1.0585x; 1.0585x over previous
//
#include <hip/hip_runtime.h>
#include <math.h>

#define BB 512
#define SS 128
#define KK 4
#define HH 128
#define DD 512   // K*H

typedef __attribute__((ext_vector_type(8))) short bf16x8;
typedef __attribute__((ext_vector_type(4))) float f32x4;

__device__ __forceinline__ unsigned short f2bf(float f) {
  unsigned u = __float_as_uint(f);
  unsigned r = u + 0x7fffu + ((u >> 16) & 1u);   // RNE (no NaNs in this data)
  return (unsigned short)(r >> 16);
}
__device__ __forceinline__ float bfhi(unsigned u) { return __uint_as_float(u & 0xffff0000u); }
__device__ __forceinline__ float bflo(unsigned u) { return __uint_as_float(u << 16); }

// async global->LDS 16B copy: lds dest is wave-uniform base + lane*16
__device__ __forceinline__ void async_cp16(const void* g, void* l) {
  __builtin_amdgcn_global_load_lds(
      (const __attribute__((address_space(1))) unsigned int*)g,
      (__attribute__((address_space(3))) unsigned int*)l, 16, 0, 0);
}

// ---------------------------------------------------------------------------
// hat[b][k][s][h'] = sum_h item[b][s][h] * w[s][k*HH+h'][h]
// FUSED f32->bf16: reads item/w fp32 directly (prep pass eliminated), converts
// during LDS staging. LDS layout identical to the proven R-prev kernel
// (128x64 bf16, rotate-granule swizzle), so the MFMA loop is unchanged.
// hat is written with a 16B-granule XOR swizzle per 256B row
// (granule c -> c ^ (s&15)) so routing_k can stage it LINEARLY via
// global_load_lds and still read both phases bank-conflict-free.
// ---------------------------------------------------------------------------
__global__ __launch_bounds__(256) void einsum_mfma(
    const float* __restrict__ item,   // f32 [B][S][H]
    const float* __restrict__ w,      // f32 [S][D][H]
    unsigned short* __restrict__ hat) // bf16 [B][K][S][H], swizzled rows
{
  __shared__ unsigned short Al[128 * 64];
  __shared__ unsigned short Wl[128 * 64];
  const int s  = blockIdx.x;
  const int b0 = (blockIdx.y & 3) * 128;
  const int dt = blockIdx.y >> 2;
  const int d0 = dt * 128;
  const int t  = threadIdx.x;
  const int lane = t & 63, wv = t >> 6;
  const int qm = wv & 1, qn = wv >> 1;
  const int n16 = lane & 15, kq = lane >> 4;
  const int cj = t & 15, r0 = t >> 4;    // staging: 4-float col / row base

  const float* Abase = item + ((size_t)b0 * SS + s) * HH;  // row stride SS*HH
  const float* Wbase = w + ((size_t)s * DD + d0) * HH;     // row stride HH

  f32x4 acc[4][4] = {};
  #pragma unroll
  for (int ks = 0; ks < 128; ks += 64) {
    if (ks) __syncthreads();             // compute(ks=0) done before overwrite
    #pragma unroll
    for (int j = 0; j < 8; j++) {
      const int r = r0 + 16 * j;
      float4 va = *(const float4*)(Abase + (size_t)r * (SS * HH) + ks + cj * 4);
      float4 vw = *(const float4*)(Wbase + (size_t)r * HH + ks + cj * 4);
      ushort4 oa, ow;
      oa.x = f2bf(va.x); oa.y = f2bf(va.y); oa.z = f2bf(va.z); oa.w = f2bf(va.w);
      ow.x = f2bf(vw.x); ow.y = f2bf(vw.y); ow.z = f2bf(vw.z); ow.w = f2bf(vw.w);
      // logical granule (cj>>1) stored at rotate-swizzled slot; 8B sub-offset
      const int goff = (((cj >> 1) + r) & 7) * 8 + (cj & 1) * 4;
      *(ushort4*)&Al[r * 64 + goff] = oa;
      *(ushort4*)&Wl[r * 64 + goff] = ow;
    }
    __syncthreads();
    #pragma unroll
    for (int kk = 0; kk < 2; kk++) {
      bf16x8 af[4], bfr[4];
      #pragma unroll
      for (int i = 0; i < 4; i++) {
        const int ra = qm * 64 + i * 16 + n16;   // w rows (h')
        const int rb = qn * 64 + i * 16 + n16;   // item rows (b)
        af[i]  = *(const bf16x8*)&Wl[ra * 64 + ((kk * 4 + kq + ra) & 7) * 8];
        bfr[i] = *(const bf16x8*)&Al[rb * 64 + ((kk * 4 + kq + rb) & 7) * 8];
      }
      #pragma unroll
      for (int i = 0; i < 4; i++)
        #pragma unroll
        for (int j = 0; j < 4; j++)
          acc[i][j] = __builtin_amdgcn_mfma_f32_16x16x32_bf16(af[i], bfr[j], acc[i][j], 0, 0, 0);
    }
  }

  // D row = qm*64+i*16+kq*4+reg = h'; col = qn*64+j*16+n16 = local b
  // hat row layout: 16 granules of 16B, physical granule = logical ^ (s&15)
  const int sx = s & 15;
  #pragma unroll
  for (int j = 0; j < 4; j++) {
    const int b = b0 + qn * 64 + j * 16 + n16;
    char* orow = (char*)(hat + (((size_t)b * KK + dt) * SS + s) * HH);
    #pragma unroll
    for (int i = 0; i < 4; i++) {
      const int h = qm * 64 + i * 16 + kq * 4;
      ushort4 o;
      o.x = f2bf(acc[i][j][0]); o.y = f2bf(acc[i][j][1]);
      o.z = f2bf(acc[i][j][2]); o.w = f2bf(acc[i][j][3]);
      *(ushort4*)(orow + ((((h >> 3) ^ sx) << 4) | ((h & 4) << 1))) = o;
    }
  }
}

// ---------------------------------------------------------------------------
// Batch-axis softmax (legacy torch dim=0) + mask zeroing. Grid (S,K).
// ---------------------------------------------------------------------------
__global__ __launch_bounds__(256) void softmax_k(
    const float* __restrict__ cw, const float* __restrict__ mask,
    float* __restrict__ sw)
{
  __shared__ float rbuf[4];
  const int s = blockIdx.x, k = blockIdx.y, t = threadIdx.x;
  const size_t base = ((size_t)k * SS + s) * BB;
  float v0 = cw[base + t], v1 = cw[base + 256 + t];
  float m = fmaxf(v0, v1);
  #pragma unroll
  for (int o = 32; o; o >>= 1) m = fmaxf(m, __shfl_xor(m, o));
  if ((t & 63) == 0) rbuf[t >> 6] = m;
  __syncthreads();
  m = fmaxf(fmaxf(rbuf[0], rbuf[1]), fmaxf(rbuf[2], rbuf[3]));
  float e0 = expf(v0 - m), e1 = expf(v1 - m);
  float ssum = e0 + e1;
  #pragma unroll
  for (int o = 32; o; o >>= 1) ssum += __shfl_xor(ssum, o);
  __syncthreads();
  if ((t & 63) == 0) rbuf[t >> 6] = ssum;
  __syncthreads();
  float inv = 1.f / (rbuf[0] + rbuf[1] + rbuf[2] + rbuf[3]);
  float m0 = mask[(size_t)t * SS + s];
  float m1 = mask[(size_t)(t + 256) * SS + s];
  sw[base + t]       = (m0 == 0.f) ? 0.f : e0 * inv;
  sw[base + 256 + t] = (m1 == 0.f) ? 0.f : e1 * inv;
}

// ---------------------------------------------------------------------------
// One routing iteration per (b,k). The 32 KB bf16 slab (pre-swizzled by
// einsum) is staged with a LINEAR global_load_lds copy — no VGPR round-trip.
// Both phases read through the same granule XOR, preserving the bank-optimal
// schedules: phase1 reads full permuted 256B rows; phase2's b128 reads land
// 8 lanes per 4-bank cluster (the 8-cycle floor).
//   mode 0: uniform sw from mask, cw  = delta
//   mode 1: sw from sw_in,        cw += delta
//   mode 2: sw from sw_in,        out = squash(cap)
// ---------------------------------------------------------------------------
__global__ __launch_bounds__(256) void routing_k(
    const unsigned short* __restrict__ hat, const float* __restrict__ mask,
    const float* __restrict__ sw_in, float* __restrict__ cw,
    float* __restrict__ out, int mode)
{
  __shared__ unsigned short hat_l[128 * 128];   // 32 KB, swizzled rows
  __shared__ float sw_l[128];
  __shared__ float4 red4[8][32];
  __shared__ float4 cq4[32];
  const int b = blockIdx.x, k = blockIdx.y, t = threadIdx.x;
  const int wv = t >> 6;

  const char* slab = (const char*)(hat + ((size_t)b * KK + k) * SS * HH);
  #pragma unroll
  for (int j = 0; j < 8; j++)                   // 8 x (64 lanes x 16B) / wave
    async_cp16(slab + j * 4096 + t * 16,
               (char*)hat_l + j * 4096 + wv * 1024);

  if (t < 128) {
    sw_l[t] = (mode == 0)
      ? ((mask[(size_t)b * SS + t] == 0.f) ? 0.f : (1.f / 512.f))
      : sw_in[((size_t)k * SS + t) * BB + b];
  }
  __syncthreads();   // drains vmcnt (global_load_lds) + lgkmcnt

  // phase 1: cap[h] = sum_s sw[s]*hat[s][h]; 8 s-groups x 32 4-elem cols
  {
    const int h4 = t & 31, sg = t >> 5;
    const char* base = (const char*)hat_l;
    float4 a = make_float4(0.f, 0.f, 0.f, 0.f);
    #pragma unroll 4
    for (int i = 0; i < 16; i++) {
      const int s = sg * 16 + i;
      uint2 v = *(const uint2*)(base + s * 256 +
                 ((((h4 >> 1) ^ (s & 15)) << 4) | ((h4 & 1) << 3)));
      float wv2 = sw_l[s];
      a.x = fmaf(wv2, bflo(v.x), a.x);
      a.y = fmaf(wv2, bfhi(v.x), a.y);
      a.z = fmaf(wv2, bflo(v.y), a.z);
      a.w = fmaf(wv2, bfhi(v.y), a.w);
    }
    red4[sg][h4] = a;
  }
  __syncthreads();

  if (t < 32) {
    float4 cap = red4[0][t];
    #pragma unroll
    for (int sg = 1; sg < 8; sg++) {
      float4 r = red4[sg][t];
      cap.x += r.x; cap.y += r.y; cap.z += r.z; cap.w += r.w;
    }
    float sq = cap.x * cap.x + cap.y * cap.y + cap.z * cap.z + cap.w * cap.w;
    #pragma unroll
    for (int o = 16; o; o >>= 1) sq += __shfl_xor(sq, o);
    const float n = sq;
    const float fac = n / (1.f + n) / sqrtf(n + 1e-9f);
    cap.x *= fac; cap.y *= fac; cap.z *= fac; cap.w *= fac;
    cq4[t] = cap;
    if (mode == 2)
      ((float4*)(out + ((size_t)b * KK + k) * HH))[t] = cap;
  }
  __syncthreads();

  if (mode < 2) {
    // phase 2: delta[s] = dot(hat[s][:], cq) — lane pair per s, from LDS
    const int s = t >> 1, hh = t & 1;
    const char* rowp = (const char*)hat_l + s * 256;
    const int sx = s & 15;
    float d = 0.f;
    #pragma unroll
    for (int j = 0; j < 8; j++) {
      uint4 v = *(const uint4*)(rowp + (((hh * 8 + j) ^ sx) << 4));
      float4 qa = cq4[hh * 16 + 2 * j];
      float4 qb = cq4[hh * 16 + 2 * j + 1];
      d += bflo(v.x) * qa.x + bfhi(v.x) * qa.y
         + bflo(v.y) * qa.z + bfhi(v.y) * qa.w
         + bflo(v.z) * qb.x + bfhi(v.z) * qb.y
         + bflo(v.w) * qb.z + bfhi(v.w) * qb.w;
    }
    d += __shfl_xor(d, 1);
    if (hh == 0) {
      float* p = cw + ((size_t)k * SS + s) * BB + b;
      if (mode == 0) *p = d; else *p += d;
    }
  }
}

extern "C" void kernel_launch(void* const* d_in, const int* in_sizes, int n_in,
                              void* d_out, int out_size, void* d_ws, size_t ws_size,
                              hipStream_t stream) {
  const float* item_eb = (const float*)d_in[0];   // [B,S,H]
  const float* mask    = (const float*)d_in[1];   // [B,S]
  const float* w       = (const float*)d_in[2];   // [1,S,K*H,H]
  float* out = (float*)d_out;                     // [B,K,H]

  char* ws = (char*)d_ws;
  unsigned short* hat_bf = (unsigned short*)ws;        // 67.1 MB [B][K][S][H]
  float* cw  = (float*)(ws + 67108864);                // 1 MB [K][S][B]
  float* swb = (float*)(ws + 68157440);                // 1 MB [K][S][B]

  einsum_mfma<<<dim3(128, 16), 256, 0, stream>>>(item_eb, w, hat_bf);

  routing_k<<<dim3(BB, KK), 256, 0, stream>>>(hat_bf, mask, nullptr, cw, out, 0);
  softmax_k<<<dim3(SS, KK), 256, 0, stream>>>(cw, mask, swb);
  routing_k<<<dim3(BB, KK), 256, 0, stream>>>(hat_bf, mask, swb, cw, out, 1);
  softmax_k<<<dim3(SS, KK), 256, 0, stream>>>(cw, mask, swb);
  routing_k<<<dim3(BB, KK), 256, 0, stream>>>(hat_bf, mask, swb, cw, out, 2);
}

// Round 2
// 172.200 us; speedup vs baseline: 1.0723x; 1.0130x over previous
//
#include <hip/hip_runtime.h>
#include <math.h>

#define BB 512
#define SS 128
#define KK 4
#define HH 128
#define DD 512   // K*H

typedef __attribute__((ext_vector_type(8))) short bf16x8;
typedef __attribute__((ext_vector_type(4))) float f32x4;

__device__ __forceinline__ unsigned short f2bf(float f) {
  unsigned u = __float_as_uint(f);
  unsigned r = u + 0x7fffu + ((u >> 16) & 1u);   // RNE (no NaNs in this data)
  return (unsigned short)(r >> 16);
}
__device__ __forceinline__ ushort4 f2bf4(float4 v) {
  ushort4 o; o.x = f2bf(v.x); o.y = f2bf(v.y); o.z = f2bf(v.z); o.w = f2bf(v.w);
  return o;
}
__device__ __forceinline__ float bfhi(unsigned u) { return __uint_as_float(u & 0xffff0000u); }
__device__ __forceinline__ float bflo(unsigned u) { return __uint_as_float(u << 16); }

// async global->LDS 16B copy: lds dest is wave-uniform base + lane*16
__device__ __forceinline__ void async_cp16(const void* g, void* l) {
  __builtin_amdgcn_global_load_lds(
      (const __attribute__((address_space(1))) unsigned int*)g,
      (__attribute__((address_space(3))) unsigned int*)l, 16, 0, 0);
}

// ---------------------------------------------------------------------------
// hat[b][k][s][h'] = sum_h item[b][s][h] * w[s][k*HH+h'][h]
// Block = (s, b-tile): A tile (128b x 128h) staged to LDS ONCE (bf16,
// 16-granule XOR swizzle), then 8 pipelined W-stage steps (4 d-tiles x 2
// K-halves) with register prefetch: next step's 8 float4 W loads are issued
// BEFORE this step's MFMA cluster, converted+written to the double-buffered
// Wl after -> loads stay in flight during every compute phase (T14).
// Grid 128x4 = 512 blocks = 2/CU (64 KB LDS), all resident, no tail.
// hat written with the 16B-granule XOR (granule ^= s&15) so routing_k can
// stage it linearly via global_load_lds and read conflict-free.
// ---------------------------------------------------------------------------
__global__ __launch_bounds__(256) void einsum_mfma(
    const float* __restrict__ item,   // f32 [B][S][H]
    const float* __restrict__ w,      // f32 [S][D][H]
    unsigned short* __restrict__ hat) // bf16 [B][K][S][H], swizzled rows
{
  __shared__ unsigned short Al[128 * 128];     // 32 KB: rows = local b, 128 h
  __shared__ unsigned short Wl[2][128 * 64];   // 2 x 16 KB K-half buffers
  const int s  = blockIdx.x;
  const int b0 = blockIdx.y * 128;
  const int t  = threadIdx.x;
  const int lane = t & 63, wvq = t >> 6;
  const int qm = wvq & 1, qn = wvq >> 1;
  const int n16 = lane & 15, kq = lane >> 4;

  const float* Abase = item + ((size_t)b0 * SS + s) * HH;  // + r*(SS*HH)
  const float* Wbase = w + (size_t)s * DD * HH;            // + (d0+r)*HH

  // ---- prologue: issue A tile + W step-0 loads, convert, park ----
  const int ac = t & 31, ar0 = t >> 5;     // A: f4-col 0..31, row base 0..7
  const int wc = t & 15, wr0 = t >> 4;     // W: f4-col 0..15, row base 0..15
  float4 apre[16];
  #pragma unroll
  for (int j = 0; j < 16; ++j)
    apre[j] = *(const float4*)(Abase + (size_t)(ar0 + 8 * j) * (SS * HH) + ac * 4);
  float4 wpre[8];
  #pragma unroll
  for (int j = 0; j < 8; ++j)
    wpre[j] = *(const float4*)(Wbase + (size_t)(wr0 + 16 * j) * HH + wc * 4);

  #pragma unroll
  for (int j = 0; j < 16; ++j) {
    const int r = ar0 + 8 * j;
    const int lg = ac >> 1;                          // logical 16B granule 0..15
    *(ushort4*)&Al[r * 128 + ((lg ^ (r & 15)) * 8) + (ac & 1) * 4] = f2bf4(apre[j]);
  }
  #pragma unroll
  for (int j = 0; j < 8; ++j) {
    const int r = wr0 + 16 * j;
    *(ushort4*)&Wl[0][r * 64 + ((((wc >> 1) + r) & 7) * 8) + (wc & 1) * 4] = f2bf4(wpre[j]);
  }
  __syncthreads();

  const int sx = s & 15;
  int buf = 0;
  for (int dt = 0; dt < 4; ++dt) {
    f32x4 acc[4][4] = {};
    #pragma unroll
    for (int hs = 0; hs < 2; ++hs) {
      const int step = dt * 2 + hs;
      if (step < 7) {                                // issue next stage EARLY
        const int d0n = ((step + 1) >> 1) * 128;
        const int ksn = ((step + 1) & 1) * 64;
        #pragma unroll
        for (int j = 0; j < 8; ++j)
          wpre[j] = *(const float4*)(Wbase + (size_t)(d0n + wr0 + 16 * j) * HH + ksn + wc * 4);
      }
      #pragma unroll
      for (int kk = 0; kk < 2; ++kk) {
        bf16x8 af[4], bfr[4];
        #pragma unroll
        for (int i = 0; i < 4; ++i) {
          const int ra = qm * 64 + i * 16 + n16;     // w rows (h')
          const int rb = qn * 64 + i * 16 + n16;     // item rows (b)
          af[i]  = *(const bf16x8*)&Wl[buf][ra * 64 + ((kk * 4 + kq + ra) & 7) * 8];
          bfr[i] = *(const bf16x8*)&Al[rb * 128 + (((hs * 8 + kk * 4 + kq) ^ (rb & 15)) * 8)];
        }
        #pragma unroll
        for (int i = 0; i < 4; ++i)
          #pragma unroll
          for (int j = 0; j < 4; ++j)
            acc[i][j] = __builtin_amdgcn_mfma_f32_16x16x32_bf16(af[i], bfr[j], acc[i][j], 0, 0, 0);
      }
      if (step < 7) {                                // write LATE, one barrier
        #pragma unroll
        for (int j = 0; j < 8; ++j) {
          const int r = wr0 + 16 * j;
          *(ushort4*)&Wl[buf ^ 1][r * 64 + ((((wc >> 1) + r) & 7) * 8) + (wc & 1) * 4] = f2bf4(wpre[j]);
        }
        __syncthreads();
        buf ^= 1;
      }
    }
    // epilogue d-tile dt: row = qm*64+i*16+kq*4+reg = h'; col = qn*64+j*16+n16 = b
    #pragma unroll
    for (int j = 0; j < 4; ++j) {
      const int b = b0 + qn * 64 + j * 16 + n16;
      char* orow = (char*)(hat + (((size_t)b * KK + dt) * SS + s) * HH);
      #pragma unroll
      for (int i = 0; i < 4; ++i) {
        const int h = qm * 64 + i * 16 + kq * 4;
        ushort4 o;
        o.x = f2bf(acc[i][j][0]); o.y = f2bf(acc[i][j][1]);
        o.z = f2bf(acc[i][j][2]); o.w = f2bf(acc[i][j][3]);
        *(ushort4*)(orow + ((((h >> 3) ^ sx) << 4) | ((h & 4) << 1))) = o;
      }
    }
  }
}

// ---------------------------------------------------------------------------
// Batch-axis softmax (legacy torch dim=0) + mask zeroing. Grid (S,K).
// ---------------------------------------------------------------------------
__global__ __launch_bounds__(256) void softmax_k(
    const float* __restrict__ cw, const float* __restrict__ mask,
    float* __restrict__ sw)
{
  __shared__ float rbuf[4];
  const int s = blockIdx.x, k = blockIdx.y, t = threadIdx.x;
  const size_t base = ((size_t)k * SS + s) * BB;
  float v0 = cw[base + t], v1 = cw[base + 256 + t];
  float m = fmaxf(v0, v1);
  #pragma unroll
  for (int o = 32; o; o >>= 1) m = fmaxf(m, __shfl_xor(m, o));
  if ((t & 63) == 0) rbuf[t >> 6] = m;
  __syncthreads();
  m = fmaxf(fmaxf(rbuf[0], rbuf[1]), fmaxf(rbuf[2], rbuf[3]));
  float e0 = expf(v0 - m), e1 = expf(v1 - m);
  float ssum = e0 + e1;
  #pragma unroll
  for (int o = 32; o; o >>= 1) ssum += __shfl_xor(ssum, o);
  __syncthreads();
  if ((t & 63) == 0) rbuf[t >> 6] = ssum;
  __syncthreads();
  float inv = 1.f / (rbuf[0] + rbuf[1] + rbuf[2] + rbuf[3]);
  float m0 = mask[(size_t)t * SS + s];
  float m1 = mask[(size_t)(t + 256) * SS + s];
  sw[base + t]       = (m0 == 0.f) ? 0.f : e0 * inv;
  sw[base + 256 + t] = (m1 == 0.f) ? 0.f : e1 * inv;
}

// ---------------------------------------------------------------------------
// One routing iteration per (b,k). Per-WAVE staging: wave wv DMAs exactly the
// 8 KB of rows [32wv, 32wv+32) that its phase-1/phase-2 lanes consume, plus
// its own 32 sw values -> a per-wave s_waitcnt replaces the block-wide
// barrier; wave 0 computes while waves 1-3 still stream (staging overlaps
// compute). First __syncthreads is only at the red4 reduction.
//   mode 0: uniform sw from mask, cw  = delta
//   mode 1: sw from sw_in,        cw += delta
//   mode 2: sw from sw_in,        out = squash(cap)
// ---------------------------------------------------------------------------
__global__ __launch_bounds__(256) void routing_k(
    const unsigned short* __restrict__ hat, const float* __restrict__ mask,
    const float* __restrict__ sw_in, float* __restrict__ cw,
    float* __restrict__ out, int mode)
{
  __shared__ unsigned short hat_l[128 * 128];   // 32 KB, swizzled rows
  __shared__ float sw_l[128];
  __shared__ float4 red4[8][32];
  __shared__ float4 cq4[32];
  const int b = blockIdx.x, k = blockIdx.y, t = threadIdx.x;
  const int wv = t >> 6, lane = t & 63;

  // wave wv stages rows [32wv, 32wv+32) = bytes [wv*8192, +8192), linearly
  const char* slab = (const char*)(hat + ((size_t)b * KK + k) * SS * HH) + wv * 8192;
  char* ldst = (char*)hat_l + wv * 8192;
  #pragma unroll
  for (int j = 0; j < 8; ++j)
    async_cp16(slab + j * 1024 + lane * 16, ldst + j * 1024);

  if (lane < 32) {                               // own wave's sw values
    const int sv = wv * 32 + lane;
    sw_l[sv] = (mode == 0)
      ? ((mask[(size_t)b * SS + sv] == 0.f) ? 0.f : (1.f / 512.f))
      : sw_in[((size_t)k * SS + sv) * BB + b];
  }
  asm volatile("s_waitcnt vmcnt(0) lgkmcnt(0)" ::: "memory");  // own loads only

  // phase 1: cap[h] = sum_s sw[s]*hat[s][h]; sg = t>>5 -> own wave's rows
  {
    const int h4 = t & 31, sg = t >> 5;
    const char* base = (const char*)hat_l;
    float4 a = make_float4(0.f, 0.f, 0.f, 0.f);
    #pragma unroll 4
    for (int i = 0; i < 16; i++) {
      const int sr = sg * 16 + i;
      uint2 v = *(const uint2*)(base + sr * 256 +
                 ((((h4 >> 1) ^ (sr & 15)) << 4) | ((h4 & 1) << 3)));
      float wv2 = sw_l[sr];
      a.x = fmaf(wv2, bflo(v.x), a.x);
      a.y = fmaf(wv2, bfhi(v.x), a.y);
      a.z = fmaf(wv2, bflo(v.y), a.z);
      a.w = fmaf(wv2, bfhi(v.y), a.w);
    }
    red4[sg][h4] = a;
  }
  __syncthreads();

  if (t < 32) {
    float4 cap = red4[0][t];
    #pragma unroll
    for (int sg = 1; sg < 8; sg++) {
      float4 r = red4[sg][t];
      cap.x += r.x; cap.y += r.y; cap.z += r.z; cap.w += r.w;
    }
    float sq = cap.x * cap.x + cap.y * cap.y + cap.z * cap.z + cap.w * cap.w;
    #pragma unroll
    for (int o = 16; o; o >>= 1) sq += __shfl_xor(sq, o);
    const float n = sq;
    const float fac = n / (1.f + n) / sqrtf(n + 1e-9f);
    cap.x *= fac; cap.y *= fac; cap.z *= fac; cap.w *= fac;
    cq4[t] = cap;
    if (mode == 2)
      ((float4*)(out + ((size_t)b * KK + k) * HH))[t] = cap;
  }

  if (mode < 2) {
    __syncthreads();
    // phase 2: delta[s] = dot(hat[s][:], cq) — s = t>>1 -> own wave's rows
    const int sr = t >> 1, hh = t & 1;
    const char* rowp = (const char*)hat_l + sr * 256;
    const int sx = sr & 15;
    float d = 0.f;
    #pragma unroll
    for (int j = 0; j < 8; j++) {
      uint4 v = *(const uint4*)(rowp + (((hh * 8 + j) ^ sx) << 4));
      float4 qa = cq4[hh * 16 + 2 * j];
      float4 qb = cq4[hh * 16 + 2 * j + 1];
      d += bflo(v.x) * qa.x + bfhi(v.x) * qa.y
         + bflo(v.y) * qa.z + bfhi(v.y) * qa.w
         + bflo(v.z) * qb.x + bfhi(v.z) * qb.y
         + bflo(v.w) * qb.z + bfhi(v.w) * qb.w;
    }
    d += __shfl_xor(d, 1);
    if (hh == 0) {
      float* p = cw + ((size_t)k * SS + sr) * BB + b;
      if (mode == 0) *p = d; else *p += d;
    }
  }
}

extern "C" void kernel_launch(void* const* d_in, const int* in_sizes, int n_in,
                              void* d_out, int out_size, void* d_ws, size_t ws_size,
                              hipStream_t stream) {
  const float* item_eb = (const float*)d_in[0];   // [B,S,H]
  const float* mask    = (const float*)d_in[1];   // [B,S]
  const float* w       = (const float*)d_in[2];   // [1,S,K*H,H]
  float* out = (float*)d_out;                     // [B,K,H]

  char* ws = (char*)d_ws;
  unsigned short* hat_bf = (unsigned short*)ws;        // 67.1 MB [B][K][S][H]
  float* cw  = (float*)(ws + 67108864);                // 1 MB [K][S][B]
  float* swb = (float*)(ws + 68157440);                // 1 MB [K][S][B]

  einsum_mfma<<<dim3(128, 4), 256, 0, stream>>>(item_eb, w, hat_bf);

  routing_k<<<dim3(BB, KK), 256, 0, stream>>>(hat_bf, mask, nullptr, cw, out, 0);
  softmax_k<<<dim3(SS, KK), 256, 0, stream>>>(cw, mask, swb);
  routing_k<<<dim3(BB, KK), 256, 0, stream>>>(hat_bf, mask, swb, cw, out, 1);
  softmax_k<<<dim3(SS, KK), 256, 0, stream>>>(cw, mask, swb);
  routing_k<<<dim3(BB, KK), 256, 0, stream>>>(hat_bf, mask, swb, cw, out, 2);
}